// Round 9
// baseline (342.854 us; speedup 1.0000x reference)
//
#include <hip/hip_runtime.h>
#include <stdint.h>

// Problem constants: B=8, S=4096, H=1024, E=8 -> N = 32768 tokens.
#define HDIM 1024
#define NEXP 8
#define NTOK 32768
#define BM 256
#define BN 256
#define BK 64

typedef __attribute__((ext_vector_type(4))) float f32x4;
typedef __attribute__((ext_vector_type(8))) short bf16x8;

// fp32 -> bf16 bits, round-to-nearest-even
__device__ __forceinline__ unsigned short f2bf(float f) {
  union { float f; unsigned u; } v; v.f = f;
  unsigned r = v.u + 0x7FFF + ((v.u >> 16) & 1);
  return (unsigned short)(r >> 16);
}

// async global->LDS, 16B per lane. LDS dest must be wave-uniform base + lane*16.
__device__ __forceinline__ void gload_lds16(const void* g, void* l) {
  __builtin_amdgcn_global_load_lds(
      (__attribute__((address_space(1))) void*)(g),
      (__attribute__((address_space(3))) void*)(l), 16, 0, 0);
}

// ---------------------------------------------------------------------------
// Kernel 1: router (fp32 exact) + x -> bf16 conversion, streaming.
// R9: R8's barrier-free WgT structure + DEPTH-2 register prefetch (R8's
// depth-1 covered only ~360 of ~900 cyc HBM latency). v0 computes while
// v1 (issued 1 chunk ago) and v2 (issued now) are in flight.
// ---------------------------------------------------------------------------
__global__ __launch_bounds__(512) void router_convert(
    const float* __restrict__ x, const float* __restrict__ Wg,
    const float* __restrict__ bg, unsigned short* __restrict__ xb,
    float* __restrict__ p) {
  __shared__ float WgT[NEXP][HDIM];  // 32 KB, WgT[e][k] = Wg[k][e]
  const int t = threadIdx.x;
  const int c4 = t & 31;       // float4 column within the 128-float chunk
  const int rh = t >> 5;       // 0..15 -> rows i*16 + rh
  const int tok0 = blockIdx.x * 64;

#pragma unroll
  for (int i = 0; i < 16; ++i) {
    const int idx = i * 512 + t;
    WgT[idx & 7][idx >> 3] = Wg[idx];
  }
  __syncthreads();

  float acc[4][NEXP] = {};
  float4 v0[4], v1[4], v2[4];
#pragma unroll
  for (int i = 0; i < 4; ++i) {
    const float* rp = x + (size_t)(tok0 + i * 16 + rh) * HDIM + c4 * 4;
    v0[i] = *(const float4*)(rp);
    v1[i] = *(const float4*)(rp + 128);
  }

#pragma unroll
  for (int ck = 0; ck < 8; ++ck) {
    if (ck < 6) {  // depth-2 prefetch
#pragma unroll
      for (int i = 0; i < 4; ++i)
        v2[i] = *(const float4*)(x + (size_t)(tok0 + i * 16 + rh) * HDIM +
                                 (ck + 2) * 128 + c4 * 4);
    }
#pragma unroll
    for (int i = 0; i < 4; ++i) {  // bf16 convert + coalesced store
      const size_t goff = (size_t)(tok0 + i * 16 + rh) * HDIM + ck * 128 + c4 * 4;
      union { unsigned short us[4]; uint2 u2; } pk;
      pk.us[0] = f2bf(v0[i].x); pk.us[1] = f2bf(v0[i].y);
      pk.us[2] = f2bf(v0[i].z); pk.us[3] = f2bf(v0[i].w);
      *(uint2*)(xb + goff) = pk.u2;
    }
#pragma unroll
    for (int e = 0; e < NEXP; ++e) {
      const f32x4 w4 = *(const f32x4*)(&WgT[e][ck * 128 + c4 * 4]);
#pragma unroll
      for (int i = 0; i < 4; ++i)
        acc[i][e] += v0[i].x * w4[0] + v0[i].y * w4[1] +
                     v0[i].z * w4[2] + v0[i].w * w4[3];
    }
#pragma unroll
    for (int i = 0; i < 4; ++i) { v0[i] = v1[i]; v1[i] = v2[i]; }
  }

#pragma unroll
  for (int i = 0; i < 4; ++i)
#pragma unroll
    for (int e = 0; e < NEXP; ++e) {
      float s = acc[i][e];
#pragma unroll
      for (int m = 16; m >= 1; m >>= 1) s += __shfl_xor(s, m);
      acc[i][e] = s;
    }

  if (c4 == 0) {
#pragma unroll
    for (int i = 0; i < 4; ++i) {
      float l[NEXP];
#pragma unroll
      for (int e = 0; e < NEXP; ++e) l[e] = acc[i][e] + bg[e];
      float mx = l[0];
#pragma unroll
      for (int e = 1; e < NEXP; ++e) mx = fmaxf(mx, l[e]);
      float s = 0.f;
#pragma unroll
      for (int e = 0; e < NEXP; ++e) s += __expf(l[e] - mx);
      p[tok0 + i * 16 + rh] = 1.0f / s;  // softmax prob of argmax = exp(0)/sum
    }
  }
}

// ---------------------------------------------------------------------------
// Kernel 2: We [k][n] fp32 -> Wt [n][k] bf16 (transpose + convert). Unchanged.
// ---------------------------------------------------------------------------
__global__ __launch_bounds__(256) void transpose_convert(
    const float* __restrict__ We, unsigned short* __restrict__ wt) {
  __shared__ float tile[64][65];
  const int bj = blockIdx.x, bi = blockIdx.y;
  const int tx = threadIdx.x & 63, ty = threadIdx.x >> 6;
#pragma unroll
  for (int i = 0; i < 16; ++i) {
    int row = i * 4 + ty;
    tile[row][tx] = We[(size_t)(bi * 64 + row) * HDIM + bj * 64 + tx];
  }
  __syncthreads();
#pragma unroll
  for (int i = 0; i < 16; ++i) {
    int row = i * 4 + ty;
    wt[(size_t)(bj * 64 + row) * HDIM + bi * 64 + tx] = f2bf(tile[tx][row]);
  }
}

// ---------------------------------------------------------------------------
// Kernel 3: C[m][n] = (A[m][:] @ We[:][n] + be[n]) * p[m], bf16 MFMA.
// R9: 8-phase-style 256x256 schedule (T3+T4+T5), keeping the measured-0-
// conflict rank-3 swizzle. 512 thr = 8 waves (2M x 4N), per-wave 128x64.
// LDS: A,B tiles 256x64 bf16, double-buffered by K-tile parity = 128 KB.
//
// Per K-tile tau (buf = tau&1): 4 phases = output quadrants. Phase 0 loads
// ALL B-frags (8 ds_read) + A-frags mf 0,1 (4); phases 1-3 load 4 A-frags.
// B is consumed in every phase's MFMA -> all B LDS reads are captured by
// phase 0's closing barrier. A-frag reads for AX rows (wave-rows 0..63)
// captured by phase 1's closing barrier; AY (64..127) by phase 3's.
//
// Half-tile definitions (staging granularity, 2 gload_lds each):
//   AX = rows {0..63,128..191}, AY = {64..127,192..255} (same for B0/B1).
// Staging schedule (issued before each phase's mid-barrier):
//   p0: stage (tau+1).AY -> OTHER buffer (its AY readers finished at
//       tau-1's phase-3 closing barrier)         [guard tau+1 < NT]
//   p1: stage (tau+2).B0 -> THIS buffer (B reads done at p0 close)
//   p2: stage (tau+2).AX -> THIS buffer (AX reads done at p1 close)
//   p3: stage (tau+2).B1 -> THIS buffer (B reads done at p0 close)
// Tile tau's 4 halves are thus issued at: AX tau-2.p2, B0 tau-2.p1,
// B1 tau-2.p3, AY tau-1.p0 -> at tau's entry the 3 newest outstanding
// halves are (tau+1).{B0,AX,B1} -> vmcnt(6) at p3 (before the closing
// barrier; barrier makes it block-wide) proves tile tau+1 fully landed.
// Never drains to 0 mid-loop (T4). Prologue: T0 full (8 loads) + T1
// {B0,AX,B1} (6 loads), vmcnt(6) -> T0 landed.
// Swizzle (R5, measured 0 conflicts): granule g = row*8+s holds k-granule
// s^(row&7); frag read slot (kk*4+q)^(col&7); staging source applies the
// XOR within the row's 128B chunk (coalescing kept, LDS dest wave-linear).
// ---------------------------------------------------------------------------
__global__ __launch_bounds__(512, 2) void moe_gemm(
    const unsigned short* __restrict__ A, const unsigned short* __restrict__ Bt,
    const float* __restrict__ be, const float* __restrict__ p,
    float* __restrict__ out) {
  __shared__ __align__(16) unsigned short As[2][BM * BK];  // 2 x 32 KB
  __shared__ __align__(16) unsigned short Bs[2][BN * BK];  // 2 x 32 KB
  const int t = threadIdx.x;

  const unsigned lin = blockIdx.x;            // 512 blocks
  const unsigned xcd = lin & 7, idx = lin >> 3;      // idx 0..63
  const int n0 = (int)(idx & 3) * BN;                // 4 n-blocks inner
  const int m0 = (int)(xcd * 16 + (idx >> 2)) * BM;  // 16 m-panels per XCD

  // staging bases: thread t covers row band r_lo = t>>3 (+64/128/192),
  // slot s0 = t&7; source granule XOR-swizzled within the 128 B row chunk.
  const int r_lo = t >> 3, s0 = t & 7;
  const int ka = (s0 ^ (r_lo & 7)) * 8;  // shorts; (r_lo+64k)&7 == r_lo&7
  const unsigned short* gA = A + (size_t)(m0 + r_lo) * HDIM + ka;
  const unsigned short* gB = Bt + (size_t)(n0 + r_lo) * HDIM + ka;

  const int lane = t & 63, wid = t >> 6;
  const int wm = (wid >> 2) * 128;       // 2 M-waves
  const int wn = (wid & 3) * 64;         // 4 N-waves
  const int col = lane & 15, q = lane >> 4;  // frag: row=col, k=q*8+i

  // half h of A for k-tile kt into As[b] (2 gload_lds); same for B.
  auto stA = [&](int b, int kt, int h) {
    const unsigned short* g = gA + kt * BK;
    if (h == 0) {
      gload_lds16(g, &As[b][(size_t)t * 8]);
      gload_lds16(g + 128 * HDIM, &As[b][(size_t)(1024 + t) * 8]);
    } else {
      gload_lds16(g + 64 * HDIM, &As[b][(size_t)(512 + t) * 8]);
      gload_lds16(g + 192 * HDIM, &As[b][(size_t)(1536 + t) * 8]);
    }
  };
  auto stB = [&](int b, int kt, int h) {
    const unsigned short* g = gB + kt * BK;
    if (h == 0) {
      gload_lds16(g, &Bs[b][(size_t)t * 8]);
      gload_lds16(g + 128 * HDIM, &Bs[b][(size_t)(1024 + t) * 8]);
    } else {
      gload_lds16(g + 64 * HDIM, &Bs[b][(size_t)(512 + t) * 8]);
      gload_lds16(g + 192 * HDIM, &Bs[b][(size_t)(1536 + t) * 8]);
    }
  };

  // frag read offsets (shorts): granule = row*8 + ((kk*4+q) ^ (col&7))
  int offA[2][8], offB[2][4];
#pragma unroll
  for (int kk = 0; kk < 2; ++kk) {
    const int sl = (kk * 4 + q) ^ (col & 7);
#pragma unroll
    for (int mf = 0; mf < 8; ++mf)
      offA[kk][mf] = ((wm + mf * 16 + col) * 8 + sl) * 8;
#pragma unroll
    for (int nf = 0; nf < 4; ++nf)
      offB[kk][nf] = ((wn + nf * 16 + col) * 8 + sl) * 8;
  }

  f32x4 acc[8][4] = {};

  // prologue: T0 complete + T1 {B0, AX, B1}; AY(T1) comes at tau=0 p0.
  stA(0, 0, 0); stA(0, 0, 1); stB(0, 0, 0); stB(0, 0, 1);
  stB(1, 1, 0); stA(1, 1, 0); stB(1, 1, 1);
  asm volatile("s_waitcnt vmcnt(6)" ::: "memory");  // T0 landed
  __builtin_amdgcn_s_barrier();

  const int NT = HDIM / BK;  // 16
  for (int tau = 0; tau < NT; ++tau) {
    const int buf = tau & 1;
    bf16x8 bfr[2][4];
#pragma unroll
    for (int ph = 0; ph < 4; ++ph) {
      // ---- ds reads for this phase ----
      if (ph == 0) {
#pragma unroll
        for (int kk = 0; kk < 2; ++kk)
#pragma unroll
          for (int nf = 0; nf < 4; ++nf)
            bfr[kk][nf] = *(const bf16x8*)(&Bs[buf][offB[kk][nf]]);
      }
      bf16x8 afr[2][2];
#pragma unroll
      for (int kk = 0; kk < 2; ++kk)
#pragma unroll
        for (int m2 = 0; m2 < 2; ++m2)
          afr[kk][m2] = *(const bf16x8*)(&As[buf][offA[kk][2 * ph + m2]]);
      // ---- staging per the proven half-tile schedule ----
      if (ph == 0 && tau + 1 < NT) stA((tau + 1) & 1, tau + 1, 1);
      if (ph == 1 && tau + 2 < NT) stB(buf, tau + 2, 0);
      if (ph == 2 && tau + 2 < NT) stA(buf, tau + 2, 0);
      if (ph == 3 && tau + 2 < NT) stB(buf, tau + 2, 1);
      __builtin_amdgcn_s_barrier();  // all reads+stage issued block-wide
      __builtin_amdgcn_s_setprio(1);
#pragma unroll
      for (int m2 = 0; m2 < 2; ++m2)
#pragma unroll
        for (int nf = 0; nf < 4; ++nf)
#pragma unroll
          for (int kk = 0; kk < 2; ++kk)
            acc[2 * ph + m2][nf] = __builtin_amdgcn_mfma_f32_16x16x32_bf16(
                afr[kk][m2], bfr[kk][nf], acc[2 * ph + m2][nf], 0, 0, 0);
      __builtin_amdgcn_s_setprio(0);
      if (ph == 3) {  // counted boundary wait (T4): next tile landed
        if (tau + 2 < NT)
          asm volatile("s_waitcnt vmcnt(6)" ::: "memory");
        else if (tau + 2 == NT)
          asm volatile("s_waitcnt vmcnt(0)" ::: "memory");
      }
      __builtin_amdgcn_s_barrier();  // closing: readers done, writers safe
    }
  }

  // epilogue: C/D layout col = lane&15 (n), row = q*4 + r (m)  [m89/m91]
  float pv[8][4];
#pragma unroll
  for (int mf = 0; mf < 8; ++mf)
#pragma unroll
    for (int r = 0; r < 4; ++r) pv[mf][r] = p[m0 + wm + mf * 16 + q * 4 + r];
#pragma unroll
  for (int nf = 0; nf < 4; ++nf) {
    const int n = n0 + wn + nf * 16 + col;
    const float bev = be[n];
#pragma unroll
    for (int mf = 0; mf < 8; ++mf) {
#pragma unroll
      for (int r = 0; r < 4; ++r) {
        const int m = m0 + wm + mf * 16 + q * 4 + r;
        out[(size_t)m * HDIM + n] = (acc[mf][nf][r] + bev) * pv[mf][r];
      }
    }
  }
}

// ---------------------------------------------------------------------------
extern "C" void kernel_launch(void* const* d_in, const int* in_sizes, int n_in,
                              void* d_out, int out_size, void* d_ws, size_t ws_size,
                              hipStream_t stream) {
  const float* x  = (const float*)d_in[0];
  const float* Wg = (const float*)d_in[1];
  const float* bg = (const float*)d_in[2];
  const float* We = (const float*)d_in[3];
  const float* be = (const float*)d_in[4];
  float* out = (float*)d_out;

  // workspace layout (needs 69,337,088 B):
  char* ws = (char*)d_ws;
  unsigned short* xb = (unsigned short*)ws;                         // 67,108,864 B
  unsigned short* wt = (unsigned short*)(ws + (size_t)67108864);    //  2,097,152 B
  float* p = (float*)(ws + (size_t)67108864 + 2097152);             //    131,072 B

  router_convert<<<NTOK / 64, 512, 0, stream>>>(x, Wg, bg, xb, p);
  transpose_convert<<<dim3(16, 16), 256, 0, stream>>>(We, wt);
  moe_gemm<<<(NTOK / BM) * (HDIM / BN), 512, 0, stream>>>(xb, wt, be, p, out);
}